// Round 18
// baseline (122.089 us; speedup 1.0000x reference)
//
#include <hip/hip_runtime.h>
#include <hip/hip_fp8.h>

#define BB 8
#define NN 4096
#define MM 4096
#define DD 128

typedef float f32x4 __attribute__((ext_vector_type(4)));
typedef long  long2v __attribute__((ext_vector_type(2)));

// ---------------------------------------------------------------------------
// Fragment-ordered fp8 layout (verified R7-R17, absmax 0): for 16-row group
// g, K-half h, the 1KB unit holds lane(quad,l15) -> 16B: row=l15 (in group),
// k=(2h+p)*32+quad*8+(0..7) at byte p*8+(k&7).
//
// LESSONS:
//  - R11/R12/R15/R16: ANY merged-finalize tail in the 4096-block main
//    regresses it. Finalize stays a separate 32-block kernel. 3 launches.
//  - R14: hipLaunchCooperativeKernel fails under this harness.
//  - R3/R4/R8/R11: explicit pipelining loses to compiler sunk loads +
//    8-waves/SIMD TLP (VGPR-64 regime).
//  - R17: balanced per-XCD patch (8nb x 64mb -> 3MB < 4MB L2): main 54->50.
//  - R18: prep decomposition (P~28us from cross-round algebra, 4x its BW
//    floor) -> 8 floats/thread, 8B stores, 4-shfl norm reduce.
// ---------------------------------------------------------------------------

// Prep: one thread per 8 consecutive k of one row (16 threads/row).
// 2x coalesced float4 loads, 4x HW cvt_pk_fp8, ONE 8B fragment-ordered
// store (contiguous for 8-aligned k), 4-level shfl norm reduce (16-lane
// row group). Also inits fwd/bsum/fsum/counter.
__global__ __launch_bounds__(256)
void prep_all(const float* __restrict__ x, const float* __restrict__ y,
              unsigned char* __restrict__ xq, unsigned char* __restrict__ yq,
              float* __restrict__ x2, float* __restrict__ y2,
              unsigned int* __restrict__ fwd, float* __restrict__ bsum,
              float* __restrict__ fsum, unsigned int* __restrict__ counter) {
    int gtid = blockIdx.x * blockDim.x + threadIdx.x;
    if (gtid < BB * MM) fwd[gtid] = 0x7f800000u;  // +inf bits
    if (gtid == 0) { *bsum = 0.0f; *fsum = 0.0f; *counter = 0u; }

    int row  = gtid >> 4;          // one row per 16 threads
    int sub8 = gtid & 15;          // 8-float chunk index within the row
    const float* src;
    unsigned char* dst;
    float* sq;
    if (row < BB * NN) {
        src = x; dst = xq; sq = x2;
    } else {
        src = y; dst = yq; sq = y2; row -= BB * NN;
    }
    const f32x4* base = (const f32x4*)(src + (size_t)row * DD + sub8 * 8);
    f32x4 v0 = base[0];
    f32x4 v1 = base[1];
    float s = v0.x * v0.x + v0.y * v0.y + v0.z * v0.z + v0.w * v0.w
            + v1.x * v1.x + v1.y * v1.y + v1.z * v1.z + v1.w * v1.w;

    // bytes [k..k+7] little-endian (verified packing, absmax 0)
    unsigned int d0 = (unsigned int)__builtin_amdgcn_cvt_pk_fp8_f32(v0.x, v0.y, 0, false);
    d0 = (unsigned int)__builtin_amdgcn_cvt_pk_fp8_f32(v0.z, v0.w, (int)d0, true);
    unsigned int d1 = (unsigned int)__builtin_amdgcn_cvt_pk_fp8_f32(v1.x, v1.y, 0, false);
    d1 = (unsigned int)__builtin_amdgcn_cvt_pk_fp8_f32(v1.z, v1.w, (int)d1, true);

    // k = sub8*8: kk=k>>5=sub8>>2, h=sub8>>3, p=(sub8>>2)&1, quad=sub8&3,
    // k&7=0 -> one contiguous 8B slot in the fragment layout.
    int h    = sub8 >> 3;
    int p    = (sub8 >> 2) & 1;
    int quad = sub8 & 3;
    size_t dstoff = ((size_t)(row >> 4) * 2 + h) * 1024
                  + (size_t)(quad * 16 + (row & 15)) * 16 + p * 8;
    uint2 d;
    d.x = d0;
    d.y = d1;
    *(uint2*)(dst + dstoff) = d;

    // norm reduce over the 16-lane row group (xor masks stay in-group)
    #pragma unroll
    for (int m = 8; m; m >>= 1) s += __shfl_xor(s, m, 64);
    if (sub8 == 0) sq[row] = s;
}

// ---------------------------------------------------------------------------
// Main: EXACT R17 (49.9us, VGPR 64, 8 waves/SIMD, fence-free, balanced
// per-XCD patch: x-stripe 1MB + y-stripe 2MB < 4MB XCD L2). UNCHANGED.
// ---------------------------------------------------------------------------
__global__ __launch_bounds__(256, 4)
void chamfer_main(const unsigned char* __restrict__ xq, const unsigned char* __restrict__ yq,
                  const float* __restrict__ x2, const float* __restrict__ y2,
                  unsigned int* __restrict__ fwd, float* __restrict__ bpart) {
    __shared__ float x2s[BB][128];          // 4 KB
    __shared__ float y2s[BB][32];           // 1 KB
    __shared__ unsigned int fbuf[BB][32];   // 1 KB
    __shared__ float red[4];

    const int tid  = threadIdx.x;
    const int lane = tid & 63;
    const int wave = tid >> 6;
    const int quad = lane >> 4;
    const int l15  = lane & 15;

    const int id  = blockIdx.x;
    const int xcd = id & 7;
    const int j   = id >> 3;                  // 0..511
    const int nb  = (xcd >> 1) * 8 + (j & 7); // 0..31 (128 n each)
    const int mb  = (xcd & 1) * 64 + (j >> 3);// 0..127 (32 m each)
    const int n0b = nb * 128;
    const int n0w = n0b + wave * 32;
    const int m0  = mb * 32;

    const size_t lane16 = (size_t)lane * 16;
    const unsigned char* xbase = xq + (size_t)(n0w >> 4) * 2048 + lane16;
    const unsigned char* ybase = yq + (size_t)(m0 >> 4) * 2048 + lane16;

    for (int i = tid; i < BB * 128; i += 256)
        x2s[i >> 7][i & 127] = x2[(size_t)(i >> 7) * NN + n0b + (i & 127)];
    if (tid < BB * 32) {
        y2s[tid >> 5][tid & 31] = y2[(size_t)(tid >> 5) * MM + m0 + (tid & 31)];
        ((unsigned int*)fbuf)[tid] = 0x7f800000u;
    }
    __syncthreads();

    long2v fx[2][2][2], fy[2][2][2];  // [buf][group][half]
    auto loadb = [&](int b, int s) {
        const unsigned char* xb = xbase + ((size_t)b << 19);  // b*256 groups*2KB
        const unsigned char* yb = ybase + ((size_t)b << 19);
        #pragma unroll
        for (int g2 = 0; g2 < 2; ++g2)
            #pragma unroll
            for (int h = 0; h < 2; ++h) {
                fx[s][g2][h] = *(const long2v*)(xb + ((g2 * 2 + h) << 10));
                fy[s][g2][h] = *(const long2v*)(yb + ((g2 * 2 + h) << 10));
            }
    };
    loadb(0, 0);

    const float INF = __builtin_inff();
    f32x4 bmin[2][2];
    #pragma unroll
    for (int fi = 0; fi < 2; ++fi)
        #pragma unroll
        for (int fj = 0; fj < 2; ++fj)
            bmin[fi][fj] = (f32x4){INF, INF, INF, INF};

    #pragma unroll 2
    for (int b = 0; b < BB; ++b) {
        const int cur = b & 1;
        if (b < BB - 1) loadb(b + 1, cur ^ 1);  // the ONLY vmem in the loop

        f32x4 acc[2][2];
        #pragma unroll
        for (int fi = 0; fi < 2; ++fi)
            #pragma unroll
            for (int fj = 0; fj < 2; ++fj)
                acc[fi][fj] = (f32x4){0.f, 0.f, 0.f, 0.f};

        #pragma unroll
        for (int h = 0; h < 2; ++h)
            #pragma unroll
            for (int p = 0; p < 2; ++p)
                #pragma unroll
                for (int fi = 0; fi < 2; ++fi)
                    #pragma unroll
                    for (int fj = 0; fj < 2; ++fj)
                        acc[fi][fj] = __builtin_amdgcn_mfma_f32_16x16x32_fp8_fp8(
                            fx[cur][fi][h][p], fy[cur][fj][h][p], acc[fi][fj], 0, 0, 0);

        float y2v[2];
        y2v[0] = y2s[b][l15];
        y2v[1] = y2s[b][16 + l15];
        float fm[2] = {INF, INF};
        #pragma unroll
        for (int fi = 0; fi < 2; ++fi) {
            const f32x4 x2v = *(const f32x4*)&x2s[b][wave * 32 + fi * 16 + quad * 4];
            #pragma unroll
            for (int fj = 0; fj < 2; ++fj)
                #pragma unroll
                for (int e = 0; e < 4; ++e) {
                    float sqv = fmaf(-2.0f, acc[fi][fj][e], x2v[e] + y2v[fj]);
                    bmin[fi][fj][e] = fminf(bmin[fi][fj][e], sqv);
                    fm[fj]          = fminf(fm[fj], sqv);
                }
        }
        #pragma unroll
        for (int fj = 0; fj < 2; ++fj) {
            atomicMin(&fbuf[b][fj * 16 + l15],
                      __float_as_uint(fmaxf(fm[fj], 0.0f)));
        }
    }
    __syncthreads();

    {
        int b = tid >> 5, c = tid & 31;
        atomicMin(&fwd[(size_t)b * MM + m0 + c], fbuf[b][c]);
    }

    float s = 0.0f;
    #pragma unroll
    for (int fi = 0; fi < 2; ++fi)
        #pragma unroll
        for (int fj = 0; fj < 2; ++fj)
            #pragma unroll
            for (int e = 0; e < 4; ++e)
                s += sqrtf(fmaxf(bmin[fi][fj][e], 0.0f));
    #pragma unroll
    for (int off = 32; off; off >>= 1) s += __shfl_down(s, off, 64);
    if (lane == 0) red[wave] = s;
    __syncthreads();
    if (tid == 0) bpart[id] = red[0] + red[1] + red[2] + red[3];
}

// Finalize: 32 blocks x 256 threads (fences live here, paid 32x not 4096x).
__global__ __launch_bounds__(256)
void finalize_kernel(const unsigned int* __restrict__ fwd,
                     const float* __restrict__ bpart,
                     float* __restrict__ bsum, float* __restrict__ fsum,
                     unsigned int* __restrict__ counter, float* __restrict__ out) {
    __shared__ float redf[4], redb[4];
    __shared__ int isLast;
    const int tid = threadIdx.x, lane = tid & 63, wave = tid >> 6;
    const int gtid = blockIdx.x * 256 + tid;
    uint4 u = ((const uint4*)fwd)[gtid];
    float sf = sqrtf(__uint_as_float(u.x)) + sqrtf(__uint_as_float(u.y)) +
               sqrtf(__uint_as_float(u.z)) + sqrtf(__uint_as_float(u.w));
    float sb = (gtid < 4096) ? bpart[gtid] : 0.0f;
    #pragma unroll
    for (int off = 32; off; off >>= 1) {
        sf += __shfl_down(sf, off, 64);
        sb += __shfl_down(sb, off, 64);
    }
    if (lane == 0) { redf[wave] = sf; redb[wave] = sb; }
    __syncthreads();
    if (tid == 0) {
        atomicAdd(fsum, redf[0] + redf[1] + redf[2] + redf[3]);
        atomicAdd(bsum, redb[0] + redb[1] + redb[2] + redb[3]);
        __threadfence();
        unsigned int c = atomicAdd(counter, 1u);
        isLast = (c == gridDim.x - 1) ? 1 : 0;
        if (isLast) {
            __threadfence();
            float fs = __hip_atomic_load(fsum, __ATOMIC_RELAXED,
                                         __HIP_MEMORY_SCOPE_AGENT);
            float bs = __hip_atomic_load(bsum, __ATOMIC_RELAXED,
                                         __HIP_MEMORY_SCOPE_AGENT);
            out[0] = fs / (float)(BB * MM) + bs / ((float)NN * (float)MM);
        }
    }
}

extern "C" void kernel_launch(void* const* d_in, const int* in_sizes, int n_in,
                              void* d_out, int out_size, void* d_ws, size_t ws_size,
                              hipStream_t stream) {
    const float* x = (const float*)d_in[0];  // (B,N,D)
    const float* y = (const float*)d_in[1];  // (B,M,D)
    float* out = (float*)d_out;

    char* w = (char*)d_ws;
    unsigned char* xq = (unsigned char*)(w);               // 4 MB fp8 (frag order)
    unsigned char* yq = (unsigned char*)(w + 4194304);     // 4 MB fp8 (frag order)
    float*    x2 = (float*)(w + 8388608);                  // 128 KB
    float*    y2 = (float*)(w + 8519680);                  // 128 KB
    unsigned int* fwd = (unsigned int*)(w + 8650752);      // 128 KB
    float*    bpart = (float*)(w + 8781824);               // 16 KB
    float*    bsum = (float*)(w + 8798208);                // 4 B
    float*    fsum = (float*)(w + 8798212);                // 4 B
    unsigned int* counter = (unsigned int*)(w + 8798216);  // 4 B

    // 65536 rows x 16 threads/row = 1.05M threads
    prep_all<<<(2 * BB * NN * 16) / 256, 256, 0, stream>>>(x, y, xq, yq, x2, y2,
                                                           fwd, bsum, fsum, counter);
    chamfer_main<<<4096, 256, 0, stream>>>(xq, yq, x2, y2, fwd, bpart);
    finalize_kernel<<<32, 256, 0, stream>>>(fwd, bpart, bsum, fsum, counter, out);
}

// Round 19
// 118.234 us; speedup vs baseline: 1.0326x; 1.0326x over previous
//
#include <hip/hip_runtime.h>
#include <hip/hip_fp8.h>

#define BB 8
#define NN 4096
#define MM 4096
#define DD 128

typedef float f32x4 __attribute__((ext_vector_type(4)));
typedef long  long2v __attribute__((ext_vector_type(2)));

// ---------------------------------------------------------------------------
// Fragment-ordered fp8 layout (verified R7-R18, absmax 0): for 16-row group
// g, K-half h, the 1KB unit holds lane(quad,l15) -> 16B: row=l15 (in group),
// k=(2h+p)*32+quad*8+(0..7) at byte p*8+(k&7).
//
// R19 trick: prep stores HALF-norms (x2/2, y2/2) and NEGATED y in fp8, so
// seeding the MFMA accumulator with C = x2/2 + y2/2 makes the matrix unit
// compute acc = sq/2 directly — deletes the 16 fmaf + 16 zero-init issue
// slots per batch from the epilogue (main is issue-slot-bound: 26+52=78%).
// sq = 2*acc folded into the final sqrt sites.
//
// LESSONS: merged finalize in the 4096-block main always regresses
// (R11/12/15/16); cooperative launch fails (R14); explicit pipelining loses
// to VGPR-64 + 8 waves/SIMD TLP (R3/4/8/11); balanced per-XCD patch keeps
// the working set under the 4MB XCD L2 (R17, FETCH 51->13MB).
// ---------------------------------------------------------------------------

// Prep: one thread per 8 consecutive k of one row (16 threads/row).
// 2x float4 loads, 4x HW cvt_pk_fp8 (y negated), ONE 8B fragment-ordered
// store, 4-level shfl HALF-norm reduce. Also inits fwd/bsum/fsum/counter.
__global__ __launch_bounds__(256)
void prep_all(const float* __restrict__ x, const float* __restrict__ y,
              unsigned char* __restrict__ xq, unsigned char* __restrict__ yq,
              float* __restrict__ x2, float* __restrict__ y2,
              unsigned int* __restrict__ fwd, float* __restrict__ bsum,
              float* __restrict__ fsum, unsigned int* __restrict__ counter) {
    int gtid = blockIdx.x * blockDim.x + threadIdx.x;
    if (gtid < BB * MM) fwd[gtid] = 0x7f800000u;  // +inf bits
    if (gtid == 0) { *bsum = 0.0f; *fsum = 0.0f; *counter = 0u; }

    int row  = gtid >> 4;          // one row per 16 threads
    int sub8 = gtid & 15;          // 8-float chunk within the row
    const float* src;
    unsigned char* dst;
    float* sq;
    float sgn;
    if (row < BB * NN) {
        src = x; dst = xq; sq = x2; sgn = 1.0f;
    } else {
        src = y; dst = yq; sq = y2; sgn = -1.0f;  // negate y: acc = sq/2
        row -= BB * NN;
    }
    const f32x4* base = (const f32x4*)(src + (size_t)row * DD + sub8 * 8);
    f32x4 v0 = base[0];
    f32x4 v1 = base[1];
    float s = v0.x * v0.x + v0.y * v0.y + v0.z * v0.z + v0.w * v0.w
            + v1.x * v1.x + v1.y * v1.y + v1.z * v1.z + v1.w * v1.w;

    unsigned int d0 = (unsigned int)__builtin_amdgcn_cvt_pk_fp8_f32(sgn * v0.x, sgn * v0.y, 0, false);
    d0 = (unsigned int)__builtin_amdgcn_cvt_pk_fp8_f32(sgn * v0.z, sgn * v0.w, (int)d0, true);
    unsigned int d1 = (unsigned int)__builtin_amdgcn_cvt_pk_fp8_f32(sgn * v1.x, sgn * v1.y, 0, false);
    d1 = (unsigned int)__builtin_amdgcn_cvt_pk_fp8_f32(sgn * v1.z, sgn * v1.w, (int)d1, true);

    int h    = sub8 >> 3;
    int p    = (sub8 >> 2) & 1;
    int quad = sub8 & 3;
    size_t dstoff = ((size_t)(row >> 4) * 2 + h) * 1024
                  + (size_t)(quad * 16 + (row & 15)) * 16 + p * 8;
    uint2 d;
    d.x = d0;
    d.y = d1;
    *(uint2*)(dst + dstoff) = d;

    #pragma unroll
    for (int m = 8; m; m >>= 1) s += __shfl_xor(s, m, 64);  // 16-lane group
    if (sub8 == 0) sq[row] = 0.5f * s;  // HALF-norm
}

// ---------------------------------------------------------------------------
// Main: R17 structure (VGPR 64, 8 waves/SIMD, fence-free, balanced XCD
// patch). Change: accumulator SEEDED with x2/2+y2/2 so acc = sq/2 — the
// fmaf+zero-init epilogue slots are gone (16 add + 32 fmin per batch).
// ---------------------------------------------------------------------------
__global__ __launch_bounds__(256, 4)
void chamfer_main(const unsigned char* __restrict__ xq, const unsigned char* __restrict__ yq,
                  const float* __restrict__ x2, const float* __restrict__ y2,
                  unsigned int* __restrict__ fwd, float* __restrict__ bpart) {
    __shared__ float x2s[BB][128];          // 4 KB (half-norms)
    __shared__ float y2s[BB][32];           // 1 KB (half-norms)
    __shared__ unsigned int fbuf[BB][32];   // 1 KB (min sq/2 bits)
    __shared__ float red[4];

    const int tid  = threadIdx.x;
    const int lane = tid & 63;
    const int wave = tid >> 6;
    const int quad = lane >> 4;
    const int l15  = lane & 15;

    const int id  = blockIdx.x;
    const int xcd = id & 7;
    const int j   = id >> 3;                  // 0..511
    const int nb  = (xcd >> 1) * 8 + (j & 7); // 0..31 (128 n each)
    const int mb  = (xcd & 1) * 64 + (j >> 3);// 0..127 (32 m each)
    const int n0b = nb * 128;
    const int n0w = n0b + wave * 32;
    const int m0  = mb * 32;

    const size_t lane16 = (size_t)lane * 16;
    const unsigned char* xbase = xq + (size_t)(n0w >> 4) * 2048 + lane16;
    const unsigned char* ybase = yq + (size_t)(m0 >> 4) * 2048 + lane16;

    for (int i = tid; i < BB * 128; i += 256)
        x2s[i >> 7][i & 127] = x2[(size_t)(i >> 7) * NN + n0b + (i & 127)];
    if (tid < BB * 32) {
        y2s[tid >> 5][tid & 31] = y2[(size_t)(tid >> 5) * MM + m0 + (tid & 31)];
        ((unsigned int*)fbuf)[tid] = 0x7f800000u;
    }
    __syncthreads();

    long2v fx[2][2][2], fy[2][2][2];  // [buf][group][half]
    auto loadb = [&](int b, int s) {
        const unsigned char* xb = xbase + ((size_t)b << 19);  // b*256 groups*2KB
        const unsigned char* yb = ybase + ((size_t)b << 19);
        #pragma unroll
        for (int g2 = 0; g2 < 2; ++g2)
            #pragma unroll
            for (int h = 0; h < 2; ++h) {
                fx[s][g2][h] = *(const long2v*)(xb + ((g2 * 2 + h) << 10));
                fy[s][g2][h] = *(const long2v*)(yb + ((g2 * 2 + h) << 10));
            }
    };
    loadb(0, 0);

    const float INF = __builtin_inff();
    f32x4 bmin[2][2];  // running min of acc = sq/2
    #pragma unroll
    for (int fi = 0; fi < 2; ++fi)
        #pragma unroll
        for (int fj = 0; fj < 2; ++fj)
            bmin[fi][fj] = (f32x4){INF, INF, INF, INF};

    #pragma unroll 2
    for (int b = 0; b < BB; ++b) {
        const int cur = b & 1;
        if (b < BB - 1) loadb(b + 1, cur ^ 1);  // the ONLY vmem in the loop

        // seed acc with (x2+y2)/2 -> MFMA (with -y fp8) yields acc = sq/2
        float y2v[2];
        y2v[0] = y2s[b][l15];
        y2v[1] = y2s[b][16 + l15];
        f32x4 x2v[2];
        #pragma unroll
        for (int fi = 0; fi < 2; ++fi)
            x2v[fi] = *(const f32x4*)&x2s[b][wave * 32 + fi * 16 + quad * 4];

        f32x4 acc[2][2];
        #pragma unroll
        for (int fi = 0; fi < 2; ++fi)
            #pragma unroll
            for (int fj = 0; fj < 2; ++fj)
                #pragma unroll
                for (int e = 0; e < 4; ++e)
                    acc[fi][fj][e] = x2v[fi][e] + y2v[fj];

        #pragma unroll
        for (int h = 0; h < 2; ++h)
            #pragma unroll
            for (int p = 0; p < 2; ++p)
                #pragma unroll
                for (int fi = 0; fi < 2; ++fi)
                    #pragma unroll
                    for (int fj = 0; fj < 2; ++fj)
                        acc[fi][fj] = __builtin_amdgcn_mfma_f32_16x16x32_fp8_fp8(
                            fx[cur][fi][h][p], fy[cur][fj][h][p], acc[fi][fj], 0, 0, 0);

        // epilogue: pure fmin (acc IS sq/2); no fmaf, no shfl, no branch
        float fm[2] = {INF, INF};
        #pragma unroll
        for (int fi = 0; fi < 2; ++fi)
            #pragma unroll
            for (int fj = 0; fj < 2; ++fj)
                #pragma unroll
                for (int e = 0; e < 4; ++e) {
                    bmin[fi][fj][e] = fminf(bmin[fi][fj][e], acc[fi][fj][e]);
                    fm[fj]          = fminf(fm[fj], acc[fi][fj][e]);
                }
        #pragma unroll
        for (int fj = 0; fj < 2; ++fj) {
            // clamp >=0 so uint ordering == float ordering; 4 quads same
            // address: no-return ds_min, pipelined
            atomicMin(&fbuf[b][fj * 16 + l15],
                      __float_as_uint(fmaxf(fm[fj], 0.0f)));
        }
    }
    __syncthreads();

    // flush forward mins (values are sq/2; finalize applies the 2x)
    {
        int b = tid >> 5, c = tid & 31;
        atomicMin(&fwd[(size_t)b * MM + m0 + c], fbuf[b][c]);
    }

    // backward: sqrt(2 * clamp(min sq/2)), block-reduce, one store/block
    float s = 0.0f;
    #pragma unroll
    for (int fi = 0; fi < 2; ++fi)
        #pragma unroll
        for (int fj = 0; fj < 2; ++fj)
            #pragma unroll
            for (int e = 0; e < 4; ++e)
                s += sqrtf(2.0f * fmaxf(bmin[fi][fj][e], 0.0f));
    #pragma unroll
    for (int off = 32; off; off >>= 1) s += __shfl_down(s, off, 64);
    if (lane == 0) red[wave] = s;
    __syncthreads();
    if (tid == 0) bpart[id] = red[0] + red[1] + red[2] + red[3];
}

// Finalize: 32 blocks x 256 threads (fences live here, paid 32x not 4096x).
// fwd holds min sq/2 -> dist = sqrt(2*v).
__global__ __launch_bounds__(256)
void finalize_kernel(const unsigned int* __restrict__ fwd,
                     const float* __restrict__ bpart,
                     float* __restrict__ bsum, float* __restrict__ fsum,
                     unsigned int* __restrict__ counter, float* __restrict__ out) {
    __shared__ float redf[4], redb[4];
    __shared__ int isLast;
    const int tid = threadIdx.x, lane = tid & 63, wave = tid >> 6;
    const int gtid = blockIdx.x * 256 + tid;
    uint4 u = ((const uint4*)fwd)[gtid];
    float sf = sqrtf(2.0f * __uint_as_float(u.x)) + sqrtf(2.0f * __uint_as_float(u.y)) +
               sqrtf(2.0f * __uint_as_float(u.z)) + sqrtf(2.0f * __uint_as_float(u.w));
    float sb = (gtid < 4096) ? bpart[gtid] : 0.0f;
    #pragma unroll
    for (int off = 32; off; off >>= 1) {
        sf += __shfl_down(sf, off, 64);
        sb += __shfl_down(sb, off, 64);
    }
    if (lane == 0) { redf[wave] = sf; redb[wave] = sb; }
    __syncthreads();
    if (tid == 0) {
        atomicAdd(fsum, redf[0] + redf[1] + redf[2] + redf[3]);
        atomicAdd(bsum, redb[0] + redb[1] + redb[2] + redb[3]);
        __threadfence();
        unsigned int c = atomicAdd(counter, 1u);
        isLast = (c == gridDim.x - 1) ? 1 : 0;
        if (isLast) {
            __threadfence();
            float fs = __hip_atomic_load(fsum, __ATOMIC_RELAXED,
                                         __HIP_MEMORY_SCOPE_AGENT);
            float bs = __hip_atomic_load(bsum, __ATOMIC_RELAXED,
                                         __HIP_MEMORY_SCOPE_AGENT);
            out[0] = fs / (float)(BB * MM) + bs / ((float)NN * (float)MM);
        }
    }
}

extern "C" void kernel_launch(void* const* d_in, const int* in_sizes, int n_in,
                              void* d_out, int out_size, void* d_ws, size_t ws_size,
                              hipStream_t stream) {
    const float* x = (const float*)d_in[0];  // (B,N,D)
    const float* y = (const float*)d_in[1];  // (B,M,D)
    float* out = (float*)d_out;

    char* w = (char*)d_ws;
    unsigned char* xq = (unsigned char*)(w);               // 4 MB fp8 (frag order)
    unsigned char* yq = (unsigned char*)(w + 4194304);     // 4 MB fp8, NEGATED
    float*    x2 = (float*)(w + 8388608);                  // 128 KB (x2/2)
    float*    y2 = (float*)(w + 8519680);                  // 128 KB (y2/2)
    unsigned int* fwd = (unsigned int*)(w + 8650752);      // 128 KB (min sq/2)
    float*    bpart = (float*)(w + 8781824);               // 16 KB
    float*    bsum = (float*)(w + 8798208);                // 4 B
    float*    fsum = (float*)(w + 8798212);                // 4 B
    unsigned int* counter = (unsigned int*)(w + 8798216);  // 4 B

    // 65536 rows x 16 threads/row = 1.05M threads
    prep_all<<<(2 * BB * NN * 16) / 256, 256, 0, stream>>>(x, y, xq, yq, x2, y2,
                                                           fwd, bsum, fsum, counter);
    chamfer_main<<<4096, 256, 0, stream>>>(xq, yq, x2, y2, fwd, bpart);
    finalize_kernel<<<32, 256, 0, stream>>>(fwd, bpart, bsum, fsum, counter, out);
}